// Round 3
// baseline (1454.293 us; speedup 1.0000x reference)
//
#include <hip/hip_runtime.h>
#include <stdint.h>

// SGL/LightGCN 3-layer propagation on MI355X (gfx950).
// ego=[200000,64] f32; 4M COO edges; per layer y[row] += val * x[col].
//
// Strategy: build CSR (counting sort by destination row) once per call,
// then gather-based SpMM: one wave per destination row, lane = embedding
// dim, register accumulation, single coalesced non-atomic 256B store per
// row. Zero f32 atomics in the hot path (only 8M cheap int atomics in the
// one-time build). d_ws layout: A, B ping-pong vectors, rowptr, cnt/cursor,
// packed {col,val} CSR edge array.

constexpr int N_USER = 100000;
constexpr int NN     = 200000;   // N_NODES
constexpr int NE     = 4000000;  // N_EDGES
constexpr int EMB    = 64;

// ---------------------------------------------------------------- init:
// A = concat(user,item); acc(d_out) = same   (one fused pass)
__global__ __launch_bounds__(256) void init_kernel(
    const float4* __restrict__ user, const float4* __restrict__ item,
    float4* __restrict__ A, float4* __restrict__ acc)
{
    const int64_t half  = (int64_t)N_USER * EMB / 4;
    const int64_t total = (int64_t)NN * EMB / 4;
    for (int64_t i = blockIdx.x * (int64_t)blockDim.x + threadIdx.x; i < total;
         i += (int64_t)gridDim.x * blockDim.x) {
        const float4 v = (i < half) ? user[i] : item[i - half];
        A[i] = v;
        acc[i] = v;
    }
}

// ---------------------------------------------------------------- hist:
// cnt[r] = degree of destination row r
__global__ __launch_bounds__(256) void hist_kernel(
    const int* __restrict__ rows, int* __restrict__ cnt)
{
    for (int e = blockIdx.x * blockDim.x + threadIdx.x; e < NE;
         e += gridDim.x * blockDim.x)
        atomicAdd(&cnt[rows[e]], 1);
}

// ---------------------------------------------------------------- scan:
// exclusive prefix sum of cnt[NN] -> rowptr[NN+1]; single workgroup.
__global__ __launch_bounds__(1024) void scan_kernel(
    const int* __restrict__ cnt, int* __restrict__ rowptr)
{
    __shared__ int sums[1024];
    const int t  = threadIdx.x;
    const int CH = (NN + 1023) / 1024;              // 196
    const int start = t * CH;
    const int end   = (start + CH < NN) ? start + CH : NN;

    int s = 0;
    for (int i = start; i < end; ++i) s += cnt[i];
    sums[t] = s;
    __syncthreads();

    // inclusive Hillis-Steele scan of the 1024 thread-sums
    for (int off = 1; off < 1024; off <<= 1) {
        const int x = sums[t];
        const int y = (t >= off) ? sums[t - off] : 0;
        __syncthreads();
        sums[t] = x + y;
        __syncthreads();
    }

    int run = (t == 0) ? 0 : sums[t - 1];           // exclusive base
    for (int i = start; i < end; ++i) {
        rowptr[i] = run;
        run += cnt[i];
    }
    if (t == 0) rowptr[NN] = sums[1023];            // == NE
}

// ---------------------------------------------------------------- scatter:
// place each edge into its row's CSR segment; packed {col, val_bits}.
__global__ __launch_bounds__(256) void scatter_kernel(
    const int* __restrict__ rows, const int* __restrict__ cols,
    const int* __restrict__ vals_bits, int* __restrict__ cursor,
    int2* __restrict__ csr_cv)
{
    for (int e = blockIdx.x * blockDim.x + threadIdx.x; e < NE;
         e += gridDim.x * blockDim.x) {
        const int r = rows[e];
        const int p = atomicAdd(&cursor[r], 1);
        csr_cv[p] = make_int2(cols[e], vals_bits[e]);
    }
}

// ---------------------------------------------------------------- spmm (CSR):
// wave per destination row; lane = embedding dim; register accumulate.
__global__ __launch_bounds__(256) void spmm_csr_kernel(
    const int* __restrict__ rowptr, const int2* __restrict__ csr_cv,
    const float* __restrict__ x, float* __restrict__ y)
{
    const int lane = threadIdx.x & 63;
    const int wave = (int)((blockIdx.x * (int64_t)blockDim.x + threadIdx.x) >> 6);
    const int nw   = (int)(((int64_t)gridDim.x * blockDim.x) >> 6);

    for (int r = wave; r < NN; r += nw) {
        const int e0 = rowptr[r];
        const int e1 = rowptr[r + 1];
        float acc = 0.f;
        #pragma unroll 4
        for (int e = e0; e < e1; ++e) {
            const int2  cv = csr_cv[e];                 // wave-uniform broadcast
            const float v  = __builtin_bit_cast(float, cv.y);
            acc = fmaf(v, x[(int64_t)cv.x * EMB + lane], acc);
        }
        y[(int64_t)r * EMB + lane] = acc;               // includes 0 for empty rows
    }
}

// ---------------------------------------------------------------- acc += y
__global__ __launch_bounds__(256) void acc_add_kernel(
    float4* __restrict__ acc, const float4* __restrict__ y)
{
    const int64_t total = (int64_t)NN * EMB / 4;
    for (int64_t i = blockIdx.x * (int64_t)blockDim.x + threadIdx.x; i < total;
         i += (int64_t)gridDim.x * blockDim.x) {
        float4 a = acc[i];
        const float4 b = y[i];
        a.x += b.x; a.y += b.y; a.z += b.z; a.w += b.w;
        acc[i] = a;
    }
}

// ---------------------------------------------------------------- acc = (acc + y) / 4
__global__ __launch_bounds__(256) void acc_final_kernel(
    float4* __restrict__ acc, const float4* __restrict__ y)
{
    const int64_t total = (int64_t)NN * EMB / 4;
    for (int64_t i = blockIdx.x * (int64_t)blockDim.x + threadIdx.x; i < total;
         i += (int64_t)gridDim.x * blockDim.x) {
        float4 a = acc[i];
        const float4 b = y[i];
        a.x = (a.x + b.x) * 0.25f;
        a.y = (a.y + b.y) * 0.25f;
        a.z = (a.z + b.z) * 0.25f;
        a.w = (a.w + b.w) * 0.25f;
        acc[i] = a;
    }
}

extern "C" void kernel_launch(void* const* d_in, const int* in_sizes, int n_in,
                              void* d_out, int out_size, void* d_ws, size_t ws_size,
                              hipStream_t stream)
{
    const float* user = (const float*)d_in[0];
    const float* item = (const float*)d_in[1];
    const int*   rows = (const int*)d_in[2];
    const int*   cols = (const int*)d_in[3];
    const int*   vals = (const int*)d_in[4];   // f32 bits

    float* acc = (float*)d_out;                // [NN, EMB]

    // ---- workspace carve-up (256B-aligned regions) ----
    char* ws = (char*)d_ws;
    const size_t VEC_B = (size_t)NN * EMB * sizeof(float);      // 51,200,000
    const size_t RP_B  = ((size_t)(NN + 1) * 4 + 255) & ~255ull; // 800,256
    const size_t CC_B  = ((size_t)NN * 4 + 255) & ~255ull;       // 800,000 -> 800,000 pad 800,  -> aligned
    float* A      = (float*)(ws);
    float* B      = (float*)(ws + VEC_B);
    int*   rowptr = (int*)  (ws + 2 * VEC_B);
    int*   cntcur = (int*)  (ws + 2 * VEC_B + RP_B);
    int2*  csr_cv = (int2*) (ws + 2 * VEC_B + RP_B + CC_B);      // 32,000,000 B
    // total ~ 136 MB

    const dim3 blk(256);
    const int eltBlocks  = 1024;   // 3.2M float4 grid-stride
    const int edgeBlocks = 2048;   // 4M edges grid-stride
    const int spmmBlocks = 4096;   // 16384 waves over 200K rows

    // ---- build phase ----
    init_kernel<<<eltBlocks, blk, 0, stream>>>(
        (const float4*)user, (const float4*)item, (float4*)A, (float4*)acc);
    hipMemsetAsync(cntcur, 0, (size_t)NN * 4, stream);
    hist_kernel<<<edgeBlocks, blk, 0, stream>>>(rows, cntcur);
    scan_kernel<<<1, 1024, 0, stream>>>(cntcur, rowptr);
    hipMemcpyAsync(cntcur, rowptr, (size_t)NN * 4, hipMemcpyDeviceToDevice, stream);
    scatter_kernel<<<edgeBlocks, blk, 0, stream>>>(rows, cols, vals, cntcur, csr_cv);

    // ---- 3 propagation layers ----
    spmm_csr_kernel<<<spmmBlocks, blk, 0, stream>>>(rowptr, csr_cv, A, B);
    acc_add_kernel<<<eltBlocks, blk, 0, stream>>>((float4*)acc, (const float4*)B);

    spmm_csr_kernel<<<spmmBlocks, blk, 0, stream>>>(rowptr, csr_cv, B, A);
    acc_add_kernel<<<eltBlocks, blk, 0, stream>>>((float4*)acc, (const float4*)A);

    spmm_csr_kernel<<<spmmBlocks, blk, 0, stream>>>(rowptr, csr_cv, A, B);
    acc_final_kernel<<<eltBlocks, blk, 0, stream>>>((float4*)acc, (const float4*)B);
}

// Round 7
// 1309.865 us; speedup vs baseline: 1.1103x; 1.1103x over previous
//
#include <hip/hip_runtime.h>
#include <stdint.h>

// SGL/LightGCN 3-layer propagation on MI355X (gfx950).
// ego=[200000,64] f32; 4M COO edges; per layer y[row] += val * x[col].
//
// v5: binned CSR build (2-level counting sort; replaces measured 344us/253MB
// line-amplified scatter) + within-run A/B of two gather-SpMM variants:
//   layer 0: spmm_wide  (wave = 4 groups x 16 lanes, float4 gathers, 8 edges
//            in flight) -- tests the latency-bound hypothesis
//   layer 1: spmm_simple (lane = dim, scalar gathers, pair-unrolled)
//   layer 2: spmm_final_wide (wide + terminal (acc+s)/4)
// All layers do identical work -> dispatch durations are directly comparable.
//
// ws: A (51.2MB) | B (51.2MB, aliased by bcv during build) | rowptr |
// bucketBase | bhist | bcursor | csr_cv (32MB). ~135MB.

constexpr int N_USER = 100000;
constexpr int NN     = 200000;            // N_NODES
constexpr int NE     = 4000000;           // N_EDGES
constexpr int EMB    = 64;
constexpr int RPB    = 64;                // rows per bucket
constexpr int NB     = NN / RPB;          // 3125 buckets (exact)
constexpr int COLB   = 18;                // col bits (200000 < 2^18)

// ---------------------------------------------------------------- init
__global__ __launch_bounds__(256) void init_kernel(
    const float4* __restrict__ user, const float4* __restrict__ item,
    float4* __restrict__ A, float4* __restrict__ acc, int* __restrict__ bhist)
{
    const int64_t half  = (int64_t)N_USER * EMB / 4;
    const int64_t total = (int64_t)NN * EMB / 4;
    const int64_t tid0  = blockIdx.x * (int64_t)blockDim.x + threadIdx.x;
    for (int64_t i = tid0; i < total; i += (int64_t)gridDim.x * blockDim.x) {
        const float4 v = (i < half) ? user[i] : item[i - half];
        A[i] = v;
        acc[i] = v;
    }
    if (tid0 < NB) bhist[tid0] = 0;
}

// ---------------------------------------------------------------- bucket hist
__global__ __launch_bounds__(256) void bhist_kernel(
    const int* __restrict__ rows, int* __restrict__ bhist)
{
    for (int e = blockIdx.x * blockDim.x + threadIdx.x; e < NE;
         e += gridDim.x * blockDim.x)
        atomicAdd(&bhist[rows[e] >> 6], 1);        // RPB = 64
}

// ---------------------------------------------------------------- bucket scan
__global__ __launch_bounds__(1024) void bscan_kernel(
    const int* __restrict__ bhist, int* __restrict__ bucketBase,
    int* __restrict__ bcursor, int* __restrict__ rowptr)
{
    __shared__ int sums[1024];
    const int t  = threadIdx.x;
    const int CH = (NB + 1023) / 1024;                 // 4
    const int start = t * CH;
    const int end   = (start + CH < NB) ? start + CH : NB;

    int s = 0;
    for (int i = start; i < end; ++i) s += bhist[i];
    sums[t] = s;
    __syncthreads();
    for (int off = 1; off < 1024; off <<= 1) {
        const int x = sums[t];
        const int y = (t >= off) ? sums[t - off] : 0;
        __syncthreads();
        sums[t] = x + y;
        __syncthreads();
    }
    int run = (t == 0) ? 0 : sums[t - 1];
    for (int i = start; i < end; ++i) {
        bucketBase[i] = run;
        bcursor[i] = 0;
        run += bhist[i];
    }
    if (t == 0) { bucketBase[NB] = NE; rowptr[NN] = NE; }
}

// ---------------------------------------------------------------- binning
__global__ __launch_bounds__(256) void bin_kernel(
    const int* __restrict__ rows, const int* __restrict__ cols,
    const int* __restrict__ vals_bits, const int* __restrict__ bucketBase,
    int* __restrict__ bcursor, int2* __restrict__ bcv)
{
    for (int e = blockIdx.x * blockDim.x + threadIdx.x; e < NE;
         e += gridDim.x * blockDim.x) {
        const int r = rows[e];
        const int b = r >> 6;
        const int p = bucketBase[b] + atomicAdd(&bcursor[b], 1);
        bcv[p] = make_int2(((r & 63) << COLB) | cols[e], vals_bits[e]);
    }
}

// ---------------------------------------------------------------- per-bucket
// LDS counting sort: emit packed CSR segment {col,val} + rowptr (64 rows).
__global__ __launch_bounds__(256) void bucket_csr_kernel(
    const int* __restrict__ bucketBase, const int2* __restrict__ bcv,
    int2* __restrict__ csr_cv, int* __restrict__ rowptr)
{
    __shared__ int lcnt[RPB];
    __shared__ int lcur[RPB];
    const int b    = blockIdx.x;
    const int t    = threadIdx.x;
    const int base = bucketBase[b];
    const int cnt  = bucketBase[b + 1] - base;

    if (t < RPB) lcnt[t] = 0;
    __syncthreads();
    for (int i = t; i < cnt; i += 256)
        atomicAdd(&lcnt[((unsigned)bcv[base + i].x) >> COLB], 1);
    __syncthreads();
    if (t < 64) {                                   // one wave scans 64 counts
        const int v = lcnt[t];
        int s = v;
        #pragma unroll
        for (int off = 1; off < 64; off <<= 1) {
            const int u = __shfl_up(s, off, 64);
            if (t >= off) s += u;
        }
        const int excl = s - v;
        lcur[t] = excl;
        rowptr[b * RPB + t] = base + excl;
    }
    __syncthreads();
    for (int i = t; i < cnt; i += 256) {
        const int2 pv = bcv[base + i];
        const int  lr = ((unsigned)pv.x) >> COLB;
        const int  p  = atomicAdd(&lcur[lr], 1);
        csr_cv[base + p] = make_int2(pv.x & ((1 << COLB) - 1), pv.y);
    }
}

// ================================================================ SpMM A:
// WIDE: wave = 4 groups x 16 lanes; group g takes edges (e-e0)%4==g; lane
// (g,sub) gathers x[col] float4 chunk sub; 2 accumulators -> 8 rows (2KB)
// in flight per wave; shfl_xor(16,32) cross-group combine; group 0 stores.
__device__ __forceinline__ float4 spmm_row_wide(
    const int* __restrict__ rowptr, const int2* __restrict__ csr_cv,
    const float4* __restrict__ x4, int r, int g, int sub)
{
    const int e0 = rowptr[r];
    const int e1 = rowptr[r + 1];
    float4 s0 = make_float4(0.f, 0.f, 0.f, 0.f);
    float4 s1 = make_float4(0.f, 0.f, 0.f, 0.f);
    int e = e0 + g;
    for (; e + 4 < e1; e += 8) {
        const int2 cv0 = csr_cv[e];
        const int2 cv1 = csr_cv[e + 4];
        const float4 x0 = x4[(int64_t)cv0.x * (EMB / 4) + sub];
        const float4 x1 = x4[(int64_t)cv1.x * (EMB / 4) + sub];
        const float v0 = __builtin_bit_cast(float, cv0.y);
        const float v1 = __builtin_bit_cast(float, cv1.y);
        s0.x = fmaf(v0, x0.x, s0.x); s0.y = fmaf(v0, x0.y, s0.y);
        s0.z = fmaf(v0, x0.z, s0.z); s0.w = fmaf(v0, x0.w, s0.w);
        s1.x = fmaf(v1, x1.x, s1.x); s1.y = fmaf(v1, x1.y, s1.y);
        s1.z = fmaf(v1, x1.z, s1.z); s1.w = fmaf(v1, x1.w, s1.w);
    }
    if (e < e1) {
        const int2 cv = csr_cv[e];
        const float4 xv = x4[(int64_t)cv.x * (EMB / 4) + sub];
        const float v = __builtin_bit_cast(float, cv.y);
        s0.x = fmaf(v, xv.x, s0.x); s0.y = fmaf(v, xv.y, s0.y);
        s0.z = fmaf(v, xv.z, s0.z); s0.w = fmaf(v, xv.w, s0.w);
    }
    float4 s = make_float4(s0.x + s1.x, s0.y + s1.y, s0.z + s1.z, s0.w + s1.w);
    s.x += __shfl_xor(s.x, 16, 64); s.y += __shfl_xor(s.y, 16, 64);
    s.z += __shfl_xor(s.z, 16, 64); s.w += __shfl_xor(s.w, 16, 64);
    s.x += __shfl_xor(s.x, 32, 64); s.y += __shfl_xor(s.y, 32, 64);
    s.z += __shfl_xor(s.z, 32, 64); s.w += __shfl_xor(s.w, 32, 64);
    return s;
}

__global__ __launch_bounds__(256) void spmm_wide_kernel(
    const int* __restrict__ rowptr, const int2* __restrict__ csr_cv,
    const float4* __restrict__ x4, float4* __restrict__ y4,
    float4* __restrict__ acc4)
{
    const int lane = threadIdx.x & 63;
    const int g    = lane >> 4;
    const int sub  = lane & 15;
    const int wave = (int)((blockIdx.x * (int64_t)blockDim.x + threadIdx.x) >> 6);
    const int nw   = (int)(((int64_t)gridDim.x * blockDim.x) >> 6);

    for (int r = wave; r < NN; r += nw) {
        const float4 s = spmm_row_wide(rowptr, csr_cv, x4, r, g, sub);
        if (g == 0) {
            const int64_t idx = (int64_t)r * (EMB / 4) + sub;
            y4[idx] = s;
            float4 a = acc4[idx];
            a.x += s.x; a.y += s.y; a.z += s.z; a.w += s.w;
            acc4[idx] = a;
        }
    }
}

__global__ __launch_bounds__(256) void spmm_final_wide_kernel(
    const int* __restrict__ rowptr, const int2* __restrict__ csr_cv,
    const float4* __restrict__ x4, float4* __restrict__ acc4)
{
    const int lane = threadIdx.x & 63;
    const int g    = lane >> 4;
    const int sub  = lane & 15;
    const int wave = (int)((blockIdx.x * (int64_t)blockDim.x + threadIdx.x) >> 6);
    const int nw   = (int)(((int64_t)gridDim.x * blockDim.x) >> 6);

    for (int r = wave; r < NN; r += nw) {
        const float4 s = spmm_row_wide(rowptr, csr_cv, x4, r, g, sub);
        if (g == 0) {
            const int64_t idx = (int64_t)r * (EMB / 4) + sub;
            float4 a = acc4[idx];
            a.x = (a.x + s.x) * 0.25f; a.y = (a.y + s.y) * 0.25f;
            a.z = (a.z + s.z) * 0.25f; a.w = (a.w + s.w) * 0.25f;
            acc4[idx] = a;
        }
    }
}

// ================================================================ SpMM B:
// SIMPLE: wave per row, lane = dim, scalar gathers, pair-unrolled.
__global__ __launch_bounds__(256) void spmm_simple_kernel(
    const int* __restrict__ rowptr, const int2* __restrict__ csr_cv,
    const float* __restrict__ x, float* __restrict__ y, float* __restrict__ acc)
{
    const int lane = threadIdx.x & 63;
    const int wave = (int)((blockIdx.x * (int64_t)blockDim.x + threadIdx.x) >> 6);
    const int nw   = (int)(((int64_t)gridDim.x * blockDim.x) >> 6);

    for (int r = wave; r < NN; r += nw) {
        const int e0 = rowptr[r];
        const int e1 = rowptr[r + 1];
        float s0 = 0.f, s1 = 0.f;
        int e = e0;
        #pragma unroll 2
        for (; e + 1 < e1; e += 2) {
            const int2 cv0 = csr_cv[e];
            const int2 cv1 = csr_cv[e + 1];
            s0 = fmaf(__builtin_bit_cast(float, cv0.y),
                      x[(int64_t)cv0.x * EMB + lane], s0);
            s1 = fmaf(__builtin_bit_cast(float, cv1.y),
                      x[(int64_t)cv1.x * EMB + lane], s1);
        }
        if (e < e1) {
            const int2 cv = csr_cv[e];
            s0 = fmaf(__builtin_bit_cast(float, cv.y),
                      x[(int64_t)cv.x * EMB + lane], s0);
        }
        const float s = s0 + s1;
        const int64_t idx = (int64_t)r * EMB + lane;
        y[idx] = s;
        acc[idx] += s;
    }
}

extern "C" void kernel_launch(void* const* d_in, const int* in_sizes, int n_in,
                              void* d_out, int out_size, void* d_ws, size_t ws_size,
                              hipStream_t stream)
{
    const float* user = (const float*)d_in[0];
    const float* item = (const float*)d_in[1];
    const int*   rows = (const int*)d_in[2];
    const int*   cols = (const int*)d_in[3];
    const int*   vals = (const int*)d_in[4];   // f32 bits

    float* acc = (float*)d_out;                // [NN, EMB]

    // ---- workspace carve-up ----
    char* ws = (char*)d_ws;
    const size_t VEC_B = (size_t)NN * EMB * sizeof(float);        // 51.2 MB
    float* A      = (float*)(ws);
    float* B      = (float*)(ws + VEC_B);
    int2*  bcv    = (int2*) (ws + VEC_B);      // aliases B during build
    char*  tail   = ws + 2 * VEC_B;
    int*   rowptr = (int*)(tail);                    tail += ((size_t)(NN + 1) * 4 + 255) & ~255ull;
    int*   bucketBase = (int*)(tail);                tail += ((size_t)(NB + 1) * 4 + 255) & ~255ull;
    int*   bhist  = (int*)(tail);                    tail += ((size_t)NB * 4 + 255) & ~255ull;
    int*   bcursor= (int*)(tail);                    tail += ((size_t)NB * 4 + 255) & ~255ull;
    int2*  csr_cv = (int2*)(tail);                   // 32 MB

    const dim3 blk(256);
    const int eltBlocks   = 1024;
    const int edgeBlocks  = 2048;
    const int wideBlocks  = 12500;  // 50K waves -> 4 rows/wave
    const int simpBlocks  = 4096;   // 16K waves -> ~12 rows/wave

    // ---- build phase ----
    init_kernel<<<eltBlocks, blk, 0, stream>>>(
        (const float4*)user, (const float4*)item, (float4*)A, (float4*)acc, bhist);
    bhist_kernel<<<edgeBlocks, blk, 0, stream>>>(rows, bhist);
    bscan_kernel<<<1, 1024, 0, stream>>>(bhist, bucketBase, bcursor, rowptr);
    bin_kernel<<<edgeBlocks, blk, 0, stream>>>(rows, cols, vals, bucketBase,
                                               bcursor, bcv);
    bucket_csr_kernel<<<NB, blk, 0, stream>>>(bucketBase, bcv, csr_cv, rowptr);

    // ---- 3 propagation layers (acc fused); layer0 vs layer1 is the A/B ----
    spmm_wide_kernel<<<wideBlocks, blk, 0, stream>>>(rowptr, csr_cv,
        (const float4*)A, (float4*)B, (float4*)acc);
    spmm_simple_kernel<<<simpBlocks, blk, 0, stream>>>(rowptr, csr_cv,
        B, A, acc);
    spmm_final_wide_kernel<<<wideBlocks, blk, 0, stream>>>(rowptr, csr_cv,
        (const float4*)A, (float4*)acc);
}